// Round 13
// baseline (136.778 us; speedup 1.0000x reference)
//
#include <hip/hip_runtime.h>

// ---------- constants (problem is fixed-shape) ----------
#define BB   16
#define PP   256
#define BP   4096        // B*P
#define DMODEL 1024
#define VV   1000
#define DLLM 4096
#define HH   16
#define DK   64
#define HDK  1024        // H*DK

using f32x4 = __attribute__((ext_vector_type(4))) float;
using s16x8 = __attribute__((ext_vector_type(8))) short;
using us8   = __attribute__((ext_vector_type(8))) unsigned short;

__device__ __forceinline__ unsigned short f2bf(float f) {
    unsigned int u = __builtin_bit_cast(unsigned int, f);
    u = (u + 0x7FFFu + ((u >> 16) & 1u)) >> 16;   // RNE
    return (unsigned short)u;
}

__device__ __forceinline__ void gload_lds16(const unsigned short* g, unsigned short* lds) {
    __builtin_amdgcn_global_load_lds(
        (const __attribute__((address_space(1))) void*)g,
        (__attribute__((address_space(3))) void*)lds,
        16, 0, 0);
}

#define WAITVM(n_) asm volatile("s_waitcnt vmcnt(%0)" :: "n"(n_) : "memory")
#define WAITLG0()  asm volatile("s_waitcnt lgkmcnt(0)" ::: "memory")
#define SBAR0()    __builtin_amdgcn_sched_barrier(0)

// ---------- MEGA1: colsum_partial ∪ cast_bf16 ∪ transpose(Wq) ∪ transpose(Wo) ----------
__device__ __forceinline__ void transpose_body(const float* __restrict__ src,
                                               unsigned short* __restrict__ dst,
                                               int R, int C, int bx, int by, int t,
                                               float (*tile)[33]) {
    int x = t & 7, y = t >> 3;                      // 8 x 32
    int c0 = bx * 32, r0 = by * 32;
    float4 v = *reinterpret_cast<const float4*>(&src[(size_t)(r0 + y) * C + c0 + x * 4]);
    tile[y][x * 4 + 0] = v.x; tile[y][x * 4 + 1] = v.y;
    tile[y][x * 4 + 2] = v.z; tile[y][x * 4 + 3] = v.w;
    __syncthreads();
    ushort4 o = make_ushort4(f2bf(tile[x * 4 + 0][y]), f2bf(tile[x * 4 + 1][y]),
                             f2bf(tile[x * 4 + 2][y]), f2bf(tile[x * 4 + 3][y]));
    *reinterpret_cast<ushort4*>(&dst[(size_t)(c0 + y) * R + r0 + x * 4]) = o;
}

__global__ void mega1(const float* __restrict__ src0, const float* __restrict__ src1,
                      float* __restrict__ part1,
                      const float* __restrict__ target, unsigned short* __restrict__ tgt_bf,
                      const float* __restrict__ Wq, unsigned short* __restrict__ wq_t,
                      const float* __restrict__ Wo, unsigned short* __restrict__ wo_t) {
    __shared__ float tile[32][33];
    int b = blockIdx.x, t = threadIdx.x;
    if (b < 320) {
        int z = b / 160, rem = b % 160, y = rem >> 2, x = rem & 3;
        int col4 = x * 256 + t;
        const float4* src = reinterpret_cast<const float4*>(z ? src1 : src0);
        int r0 = y * 25;
        float4 acc = make_float4(0.f, 0.f, 0.f, 0.f);
        for (int r = 0; r < 25; ++r) {
            float4 v = src[(size_t)(r0 + r) * (DLLM / 4) + col4];
            acc.x += v.x; acc.y += v.y; acc.z += v.z; acc.w += v.w;
        }
        reinterpret_cast<float4*>(part1)[(size_t)(z * 40 + y) * (DLLM / 4) + col4] = acc;
    } else if (b < 320 + 2048) {
        int idx = (b - 320) * 256 + t;
        float4 v0 = reinterpret_cast<const float4*>(target)[idx * 2];
        float4 v1 = reinterpret_cast<const float4*>(target)[idx * 2 + 1];
        us8 o = { f2bf(v0.x), f2bf(v0.y), f2bf(v0.z), f2bf(v0.w),
                  f2bf(v1.x), f2bf(v1.y), f2bf(v1.z), f2bf(v1.w) };
        *reinterpret_cast<us8*>(&tgt_bf[(size_t)idx * 8]) = o;
    } else if (b < 320 + 2048 + 1024) {
        int b2 = b - 2368;
        transpose_body(Wq, wq_t, DMODEL, HDK, b2 & 31, b2 >> 5, t, tile);
    } else {
        int b2 = b - 3392;
        transpose_body(Wo, wo_t, HDK, DLLM, b2 & 127, b2 >> 7, t, tile);
    }
}

// ---------- gemv_partial2 (inlines colsum_reduce) ----------
__global__ void gemv_partial2(const float* __restrict__ Wk, const float* __restrict__ Wv,
                              const float* __restrict__ part1, float* __restrict__ part2) {
    __shared__ float vec[64];
    int c     = blockIdx.x * 256 + threadIdx.x;
    int chunk = blockIdx.y;
    int z     = blockIdx.z;
    const float* W = z ? Wv : Wk;
    if (threadIdx.x < 64) {
        int r = chunk * 64 + threadIdx.x;
        float a = 0.f;
        for (int p = 0; p < 40; ++p)
            a += part1[(size_t)(z * 40 + p) * DLLM + r];
        vec[threadIdx.x] = a;
    }
    __syncthreads();
    float acc = 0.f;
    int r0 = chunk * 64;
    for (int r = 0; r < 64; ++r)
        acc += vec[r] * W[(size_t)(r0 + r) * HDK + c];
    part2[((z * 64 + chunk) * HDK) + c] = acc;
}

__global__ void gemv_reduce(const float* __restrict__ part,
                            const float* __restrict__ bk, const float* __restrict__ bv,
                            float* __restrict__ kvsum) {
    int idx = blockIdx.x * 256 + threadIdx.x;
    int z = idx >> 10, c = idx & 1023;
    float acc = 0.f;
    for (int ch = 0; ch < 64; ++ch) acc += part[(size_t)(z * 64 + ch) * HDK + c];
    acc += (float)VV * (z ? bv[c] : bk[c]);
    kvsum[idx] = acc;
}

// ---------- GEMM1: r10's proven counted-vmcnt 3-buffer kernel (EPI=1 only) ----------
template<int EPI, int BMt, int BNt, int WM, int WN, int BMPX, int NXBN, int BNPX>
__global__ __launch_bounds__(WM * WN * 64, 2)
void gemm_ctd3(const unsigned short* __restrict__ A, const unsigned short* __restrict__ Bt,
               float* __restrict__ C, const float* __restrict__ bias,
               const float* __restrict__ kvsum, unsigned short* __restrict__ R,
               int N, int K) {
    constexpr int WAVES = WM * WN;
    constexpr int Mw = BMt / WM;
    constexpr int M_REP = Mw / 16;
    constexpr int NA = BMt * 32 / (WAVES * 512);
    constexpr int NB = BNt * 32 / (WAVES * 512);
    constexpr int NST = NA + NB;
    static_assert(BNt / WN == 64, "wave col span must be 64");

    __shared__ __align__(16) unsigned short Asm[3][BMt * 32];
    __shared__ __align__(16) unsigned short Bsm[3][BNt * 32];

    const int xcd = blockIdx.x & 7, l = blockIdx.x >> 3;
    const int bm = ((xcd / NXBN) * BMPX + (l % BMPX)) * BMt;
    const int bn = ((xcd % NXBN) * BNPX + (l / BMPX)) * BNt;

    const int t = threadIdx.x;
    const int w = t >> 6, lane = t & 63;
    const int wr = w / WN, wc = w % WN;
    const int l15 = lane & 15, kgrp = lane >> 4;

    size_t goffA[NA], goffB[NB];
    int ldsoA[NA], ldsoB[NB];
    {
        int s8 = lane & 7, jj = lane >> 3;
#pragma unroll
        for (int i = 0; i < NA; ++i) {
            int sr = (i * WAVES + w) * 8 + jj;
            int x = s8 ^ (sr & 7);
            goffA[i] = (size_t)(bm + sr * 2 + (x >> 2)) * K + (x & 3) * 8;
            ldsoA[i] = (i * WAVES + w) * 512;
        }
#pragma unroll
        for (int i = 0; i < NB; ++i) {
            int sr = (i * WAVES + w) * 8 + jj;
            int x = s8 ^ (sr & 7);
            goffB[i] = (size_t)(bn + sr * 2 + (x >> 2)) * K + (x & 3) * 8;
            ldsoB[i] = (i * WAVES + w) * 512;
        }
    }
    int ra[M_REP], rb[4];
#pragma unroll
    for (int m = 0; m < M_REP; ++m) {
        int r = wr * Mw + m * 16 + l15;
        int s8 = (kgrp + 4 * (r & 1)) ^ ((r >> 1) & 7);
        ra[m] = (r >> 1) * 64 + s8 * 8;
    }
#pragma unroll
    for (int n = 0; n < 4; ++n) {
        int r = wc * 64 + n * 16 + l15;
        int s8 = (kgrp + 4 * (r & 1)) ^ ((r >> 1) & 7);
        rb[n] = (r >> 1) * 64 + s8 * 8;
    }

    f32x4 acc[M_REP][4] = {};

#define STG(t_, b_) do { size_t k0_ = (size_t)(t_) * 32;               \
    _Pragma("unroll")                                                  \
    for (int i_ = 0; i_ < NA; ++i_)                                    \
        gload_lds16(A + goffA[i_] + k0_, &Asm[b_][ldsoA[i_]]);         \
    _Pragma("unroll")                                                  \
    for (int i_ = 0; i_ < NB; ++i_)                                    \
        gload_lds16(Bt + goffB[i_] + k0_, &Bsm[b_][ldsoB[i_]]); } while (0)

    const int nT = K >> 5;
    STG(0, 0); STG(1, 1);
    WAITVM(NST);
    __builtin_amdgcn_s_barrier();

    int cur = 0;
    for (int tk = 0; tk < nT; ++tk) {
        s16x8 af[M_REP], bfr[4];
#pragma unroll
        for (int m = 0; m < M_REP; ++m)
            af[m] = *reinterpret_cast<const s16x8*>(&Asm[cur][ra[m]]);
#pragma unroll
        for (int n = 0; n < 4; ++n)
            bfr[n] = *reinterpret_cast<const s16x8*>(&Bsm[cur][rb[n]]);
        if (tk + 2 < nT) STG(tk + 2, cur == 0 ? 2 : cur - 1);
        __builtin_amdgcn_s_setprio(1);
#pragma unroll
        for (int m = 0; m < M_REP; ++m)
#pragma unroll
            for (int n = 0; n < 4; ++n)
                acc[m][n] = __builtin_amdgcn_mfma_f32_16x16x32_bf16(af[m], bfr[n], acc[m][n], 0, 0, 0);
        __builtin_amdgcn_s_setprio(0);
        if (tk + 2 < nT)      WAITVM(NST);
        else if (tk + 1 < nT) WAITVM(0);
        if (tk + 1 < nT) __builtin_amdgcn_s_barrier();
        cur = (cur == 2) ? 0 : cur + 1;
    }
#undef STG

    // fused per-head softmax epilogue (wave spans one 64-col head)
    float bqv[4], ksv[4], vsv[4];
#pragma unroll
    for (int n = 0; n < 4; ++n) {
        int col = bn + wc * 64 + n * 16 + l15;
        bqv[n] = bias[col];
        ksv[n] = kvsum[col];
        vsv[n] = kvsum[HDK + col];
    }
#pragma unroll
    for (int m = 0; m < M_REP; ++m) {
        int grow = bm + wr * Mw + m * 16 + kgrp * 4;
#pragma unroll
        for (int j = 0; j < 4; ++j) {
            float x[4];
#pragma unroll
            for (int n = 0; n < 4; ++n)
                x[n] = 0.125f * (acc[m][n][j] + bqv[n]) * ksv[n];
            float mx = fmaxf(fmaxf(x[0], x[1]), fmaxf(x[2], x[3]));
#pragma unroll
            for (int off = 8; off; off >>= 1) mx = fmaxf(mx, __shfl_xor(mx, off));
            float e[4], s = 0.f;
#pragma unroll
            for (int n = 0; n < 4; ++n) { e[n] = __expf(x[n] - mx); s += e[n]; }
#pragma unroll
            for (int off = 8; off; off >>= 1) s += __shfl_xor(s, off);
            float inv = 1.0f / s;
#pragma unroll
            for (int n = 0; n < 4; ++n) {
                int col = bn + wc * 64 + n * 16 + l15;
                R[(size_t)(grow + j) * N + col] = f2bf(e[n] * inv * vsv[n]);
            }
        }
    }
}

// ---------- GEMM2: barrier-free single-wave kernel ----------
// One wave per block, wave-private double-buffered LDS (32KB). NO s_barrier
// anywhere: the wave's own gload_lds -> vmcnt -> ds_read -> lgkmcnt chain is
// self-consistent. 4 independent blocks/CU self-skew: one wave's MFMA cluster
// fills another's LDS/L2 service time — no cross-wave convoys (r5-r12's
// lockstep barriers serialized the pipes at ~26-29% MfmaUtil).
// Wave tile 128x128 (64 MFMA/K-tile), BK=32, counted vmcnt(16) distance-2
// prefetch, A-frags reg-double-buffered (fa0/fa1 named, rule #20), B-frags
// single-set read after the MFMA cluster (WAR dep keeps order).
// sched_barrier(0) after every waitcnt (rule #18: reg-only MFMA can hoist
// past inline-asm waits). LDS involution swizzle (r10's, 0 conflicts).
template<int BM, int BN, int K, int NXBN, int BMPX, int BNPX>
__global__ __launch_bounds__(64, 1)
void gemm_wave(const unsigned short* __restrict__ A, const unsigned short* __restrict__ Bt,
               float* __restrict__ C, const float* __restrict__ bias, int N) {
    constexpr int M_REP = BM / 16, N_REP = BN / 16;
    constexpr int NLA = BM / 16, NLB = BN / 16;      // gload_lds instrs per tile
    constexpr int NST = NLA + NLB;                    // vm-ops per staged tile
    constexpr int AW = BM * 32;                       // ushorts of A region
    constexpr int nT = K / 32;
    static_assert(nT % 2 == 0 && nT >= 4, "K-tiling");
    __shared__ __align__(16) unsigned short lds[2][AW + BN * 32];

    // rect-per-XCD swizzle
    const int xcd = blockIdx.x & 7, l = blockIdx.x >> 3;
    const int bm = ((xcd / NXBN) * BMPX + (l % BMPX)) * BM;
    const int bn = ((xcd % NXBN) * BNPX + (l / BMPX)) * BN;

    const int lane = threadIdx.x;
    const int l15 = lane & 15, kgrp = lane >> 4;

    // staging source (pre-swizzled): per 1KB instr lane covers super-row
    // jj=lane>>3 (8 srs = 16 rows), phys slot s8=lane&7; logical x = s8^jj
    // (i*8 preserves sr&7 across instrs).
    const int s8 = lane & 7, jj = lane >> 3;
    const int xs = s8 ^ jj;
    const int srow = jj * 2 + (xs >> 2);
    const int scol = (xs & 3) * 8;
    const unsigned short* gA0 = A + (size_t)(bm + srow) * K + scol;
    const unsigned short* gB0 = Bt + (size_t)(bn + srow) * K + scol;

    // ds_read lane offset (ushorts); frag m adds m*512 (sr&7 invariant in m)
    const int roff = (l15 >> 1) * 64 + (((kgrp + 4 * (l15 & 1)) ^ ((l15 >> 1) & 7)) * 8);

    f32x4 acc[M_REP][N_REP] = {};
    s16x8 fa0[M_REP], fa1[M_REP], fb[N_REP];

#define STAGE(tk_, b_) do {                                            \
    const unsigned short* ga_ = gA0 + (size_t)(tk_) * 32;              \
    unsigned short* la_ = &lds[b_][0];                                 \
    _Pragma("unroll 1")                                                \
    for (int i_ = 0; i_ < NLA; ++i_) {                                 \
        gload_lds16(ga_, la_); ga_ += (size_t)16 * K; la_ += 512; }    \
    const unsigned short* gb_ = gB0 + (size_t)(tk_) * 32;              \
    unsigned short* lb_ = &lds[b_][AW];                                \
    _Pragma("unroll 1")                                                \
    for (int i_ = 0; i_ < NLB; ++i_) {                                 \
        gload_lds16(gb_, lb_); gb_ += (size_t)16 * K; lb_ += 512; } } while (0)

#define READF_A(fa_, b_) do { _Pragma("unroll")                        \
    for (int m_ = 0; m_ < M_REP; ++m_)                                 \
        fa_[m_] = *reinterpret_cast<const s16x8*>(&lds[b_][m_ * 512 + roff]); } while (0)
#define READF_B(b_) do { _Pragma("unroll")                             \
    for (int n_ = 0; n_ < N_REP; ++n_)                                 \
        fb[n_] = *reinterpret_cast<const s16x8*>(&lds[b_][AW + n_ * 512 + roff]); } while (0)
#define MFMAS(fa_) do { _Pragma("unroll")                              \
    for (int m_ = 0; m_ < M_REP; ++m_)                                 \
        _Pragma("unroll")                                              \
        for (int n_ = 0; n_ < N_REP; ++n_)                             \
            acc[m_][n_] = __builtin_amdgcn_mfma_f32_16x16x32_bf16(     \
                fa_[m_], fb[n_], acc[m_][n_], 0, 0, 0); } while (0)

    // prologue
    STAGE(0, 0); STAGE(1, 1);
    WAITVM(NST); SBAR0();            // tile0 landed (tile1's NST in flight)
    READF_A(fa0, 0); READF_B(0);
    WAITLG0(); SBAR0();

    for (int tk = 0; tk < nT; tk += 2) {
        // even: MFMA tile tk (fa0/fb); read tile tk+1; stage tk+2 into buf0
        if (tk + 2 < nT) { STAGE(tk + 2, 0); WAITVM(NST); }
        else             { WAITVM(0); }
        SBAR0();
        READF_A(fa1, 1);
        MFMAS(fa0);
        READF_B(1);                  // WAR on fb keeps this after MFMAS
        WAITLG0(); SBAR0();
        // odd: MFMA tile tk+1 (fa1/fb); read tile tk+2; stage tk+3 into buf1
        if (tk + 3 < nT)      { STAGE(tk + 3, 1); WAITVM(NST); }
        else if (tk + 2 < nT) { WAITVM(0); }
        SBAR0();
        if (tk + 2 < nT) READF_A(fa0, 0);
        MFMAS(fa1);
        if (tk + 2 < nT) READF_B(0);
        WAITLG0(); SBAR0();
    }
#undef STAGE
#undef READF_A
#undef READF_B
#undef MFMAS

    // epilogue: C/D layout col = lane&15, row = (lane>>4)*4 + j
#pragma unroll
    for (int m = 0; m < M_REP; ++m) {
        int grow = bm + m * 16 + kgrp * 4;
#pragma unroll
        for (int n = 0; n < N_REP; ++n) {
            int gcol = bn + n * 16 + l15;
            float bb = bias[gcol];
#pragma unroll
            for (int j = 0; j < 4; ++j)
                C[(size_t)(grow + j) * N + gcol] = acc[m][n][j] + bb;
        }
    }
}

// ---------- host launch ----------
extern "C" void kernel_launch(void* const* d_in, const int* in_sizes, int n_in,
                              void* d_out, int out_size, void* d_ws, size_t ws_size,
                              hipStream_t stream) {
    const float* target = (const float*)d_in[0];
    const float* source = (const float*)d_in[1];
    const float* value  = (const float*)d_in[2];
    const float* Wq = (const float*)d_in[3];
    const float* bq = (const float*)d_in[4];
    const float* Wk = (const float*)d_in[5];
    const float* bk = (const float*)d_in[6];
    const float* Wv = (const float*)d_in[7];
    const float* bv = (const float*)d_in[8];
    const float* Wo = (const float*)d_in[9];
    const float* bo = (const float*)d_in[10];
    float* out = (float*)d_out;

    char* ws = (char*)d_ws;
    float*          part1  = (float*)(ws);                      // 1.25MB
    float*          part2  = (float*)(ws + 0x180000);           // 512KB
    float*          kvsum  = (float*)(ws + 0x210000);           // 8KB
    unsigned short* tgt_bf = (unsigned short*)(ws + 0x400000);  // 8MB
    unsigned short* wq_t   = (unsigned short*)(ws + 0xC00000);  // 2MB
    unsigned short* wo_t   = (unsigned short*)(ws + 0xE00000);  // 8MB
    unsigned short* Rb     = (unsigned short*)(ws + 0x1600000); // 8MB

    // 1) fused prep: colsum partials + cast(target) + transpose(Wq) + transpose(Wo)
    mega1<<<7488, 256, 0, stream>>>(source, value, part1, target, tgt_bf, Wq, wq_t, Wo, wo_t);

    // 2) Ksum/Vsum GEMV + bias fold
    gemv_partial2<<<dim3(4, 64, 2), 256, 0, stream>>>(Wk, Wv, part1, part2);
    gemv_reduce<<<8, 256, 0, stream>>>(part2, bk, bv, kvsum);

    // 3) fused: S = target @ Wq; R = softmax_head(0.125*(S+bq)*Ksum) * Vsum (bf16)
    //    r10's proven config: 64x128, grid 512, 2 blocks/CU.
    gemm_ctd3<1, 64, 128, 2, 2, 16, 2, 4><<<512, 256, 0, stream>>>(
        tgt_bf, wq_t, nullptr, bq, kvsum, Rb, HDK, DMODEL);

    // 4) out = R @ Wo + bo — barrier-free single-wave kernel.
    //    128x128 per wave, grid 1024 = exactly 4 blocks/CU (32KB LDS each),
    //    per-XCD rect 16bm x 8bn.
    gemm_wave<128, 128, 1024, 4, 16, 8><<<1024, 64, 0, stream>>>(
        Rb, wo_t, out, bo, DLLM);
}

// Round 14
// 105.486 us; speedup vs baseline: 1.2966x; 1.2966x over previous
//
#include <hip/hip_runtime.h>

// ---------- constants (problem is fixed-shape) ----------
#define BB   16
#define PP   256
#define BP   4096        // B*P
#define DMODEL 1024
#define VV   1000
#define DLLM 4096
#define HH   16
#define DK   64
#define HDK  1024        // H*DK

using f32x4 = __attribute__((ext_vector_type(4))) float;
using s16x8 = __attribute__((ext_vector_type(8))) short;
using us8   = __attribute__((ext_vector_type(8))) unsigned short;

__device__ __forceinline__ unsigned short f2bf(float f) {
    unsigned int u = __builtin_bit_cast(unsigned int, f);
    u = (u + 0x7FFFu + ((u >> 16) & 1u)) >> 16;   // RNE
    return (unsigned short)u;
}

__device__ __forceinline__ void gload_lds16(const unsigned short* g, unsigned short* lds) {
    __builtin_amdgcn_global_load_lds(
        (const __attribute__((address_space(1))) void*)g,
        (__attribute__((address_space(3))) void*)lds,
        16, 0, 0);
}

#define WAITVM(n_) asm volatile("s_waitcnt vmcnt(%0)" :: "n"(n_) : "memory")

// ---------- MEGA1: colsum_partial ∪ cast_bf16 ∪ transpose(Wq) ∪ transpose(Wo) ----------
__device__ __forceinline__ void transpose_body(const float* __restrict__ src,
                                               unsigned short* __restrict__ dst,
                                               int R, int C, int bx, int by, int t,
                                               float (*tile)[33]) {
    int x = t & 7, y = t >> 3;                      // 8 x 32
    int c0 = bx * 32, r0 = by * 32;
    float4 v = *reinterpret_cast<const float4*>(&src[(size_t)(r0 + y) * C + c0 + x * 4]);
    tile[y][x * 4 + 0] = v.x; tile[y][x * 4 + 1] = v.y;
    tile[y][x * 4 + 2] = v.z; tile[y][x * 4 + 3] = v.w;
    __syncthreads();
    ushort4 o = make_ushort4(f2bf(tile[x * 4 + 0][y]), f2bf(tile[x * 4 + 1][y]),
                             f2bf(tile[x * 4 + 2][y]), f2bf(tile[x * 4 + 3][y]));
    *reinterpret_cast<ushort4*>(&dst[(size_t)(c0 + y) * R + r0 + x * 4]) = o;
}

__global__ void mega1(const float* __restrict__ src0, const float* __restrict__ src1,
                      float* __restrict__ part1,
                      const float* __restrict__ target, unsigned short* __restrict__ tgt_bf,
                      const float* __restrict__ Wq, unsigned short* __restrict__ wq_t,
                      const float* __restrict__ Wo, unsigned short* __restrict__ wo_t) {
    __shared__ float tile[32][33];
    int b = blockIdx.x, t = threadIdx.x;
    if (b < 320) {
        int z = b / 160, rem = b % 160, y = rem >> 2, x = rem & 3;
        int col4 = x * 256 + t;
        const float4* src = reinterpret_cast<const float4*>(z ? src1 : src0);
        int r0 = y * 25;
        float4 acc = make_float4(0.f, 0.f, 0.f, 0.f);
        for (int r = 0; r < 25; ++r) {
            float4 v = src[(size_t)(r0 + r) * (DLLM / 4) + col4];
            acc.x += v.x; acc.y += v.y; acc.z += v.z; acc.w += v.w;
        }
        reinterpret_cast<float4*>(part1)[(size_t)(z * 40 + y) * (DLLM / 4) + col4] = acc;
    } else if (b < 320 + 2048) {
        int idx = (b - 320) * 256 + t;
        float4 v0 = reinterpret_cast<const float4*>(target)[idx * 2];
        float4 v1 = reinterpret_cast<const float4*>(target)[idx * 2 + 1];
        us8 o = { f2bf(v0.x), f2bf(v0.y), f2bf(v0.z), f2bf(v0.w),
                  f2bf(v1.x), f2bf(v1.y), f2bf(v1.z), f2bf(v1.w) };
        *reinterpret_cast<us8*>(&tgt_bf[(size_t)idx * 8]) = o;
    } else if (b < 320 + 2048 + 1024) {
        int b2 = b - 2368;
        transpose_body(Wq, wq_t, DMODEL, HDK, b2 & 31, b2 >> 5, t, tile);
    } else {
        int b2 = b - 3392;
        transpose_body(Wo, wo_t, HDK, DLLM, b2 & 127, b2 >> 7, t, tile);
    }
}

// ---------- gemv_partial2 (inlines colsum_reduce) ----------
__global__ void gemv_partial2(const float* __restrict__ Wk, const float* __restrict__ Wv,
                              const float* __restrict__ part1, float* __restrict__ part2) {
    __shared__ float vec[64];
    int c     = blockIdx.x * 256 + threadIdx.x;
    int chunk = blockIdx.y;
    int z     = blockIdx.z;
    const float* W = z ? Wv : Wk;
    if (threadIdx.x < 64) {
        int r = chunk * 64 + threadIdx.x;
        float a = 0.f;
        for (int p = 0; p < 40; ++p)
            a += part1[(size_t)(z * 40 + p) * DLLM + r];
        vec[threadIdx.x] = a;
    }
    __syncthreads();
    float acc = 0.f;
    int r0 = chunk * 64;
    for (int r = 0; r < 64; ++r)
        acc += vec[r] * W[(size_t)(r0 + r) * HDK + c];
    part2[((z * 64 + chunk) * HDK) + c] = acc;
}

__global__ void gemv_reduce(const float* __restrict__ part,
                            const float* __restrict__ bk, const float* __restrict__ bv,
                            float* __restrict__ kvsum) {
    int idx = blockIdx.x * 256 + threadIdx.x;
    int z = idx >> 10, c = idx & 1023;
    float acc = 0.f;
    for (int ch = 0; ch < 64; ++ch) acc += part[(size_t)(z * 64 + ch) * HDK + c];
    acc += (float)VV * (z ? bv[c] : bk[c]);
    kvsum[idx] = acc;
}

// ---------- GEMM1: r10's proven counted-vmcnt 3-buffer kernel (fused softmax) ----------
template<int EPI, int BMt, int BNt, int WM, int WN, int BMPX, int NXBN, int BNPX>
__global__ __launch_bounds__(WM * WN * 64, 2)
void gemm_ctd3(const unsigned short* __restrict__ A, const unsigned short* __restrict__ Bt,
               float* __restrict__ C, const float* __restrict__ bias,
               const float* __restrict__ kvsum, unsigned short* __restrict__ R,
               int N, int K) {
    constexpr int WAVES = WM * WN;
    constexpr int Mw = BMt / WM;
    constexpr int M_REP = Mw / 16;
    constexpr int NA = BMt * 32 / (WAVES * 512);
    constexpr int NB = BNt * 32 / (WAVES * 512);
    constexpr int NST = NA + NB;
    static_assert(BNt / WN == 64, "wave col span must be 64");

    __shared__ __align__(16) unsigned short Asm[3][BMt * 32];
    __shared__ __align__(16) unsigned short Bsm[3][BNt * 32];

    const int xcd = blockIdx.x & 7, l = blockIdx.x >> 3;
    const int bm = ((xcd / NXBN) * BMPX + (l % BMPX)) * BMt;
    const int bn = ((xcd % NXBN) * BNPX + (l / BMPX)) * BNt;

    const int t = threadIdx.x;
    const int w = t >> 6, lane = t & 63;
    const int wr = w / WN, wc = w % WN;
    const int l15 = lane & 15, kgrp = lane >> 4;

    size_t goffA[NA], goffB[NB];
    int ldsoA[NA], ldsoB[NB];
    {
        int s8 = lane & 7, jj = lane >> 3;
#pragma unroll
        for (int i = 0; i < NA; ++i) {
            int sr = (i * WAVES + w) * 8 + jj;
            int x = s8 ^ (sr & 7);
            goffA[i] = (size_t)(bm + sr * 2 + (x >> 2)) * K + (x & 3) * 8;
            ldsoA[i] = (i * WAVES + w) * 512;
        }
#pragma unroll
        for (int i = 0; i < NB; ++i) {
            int sr = (i * WAVES + w) * 8 + jj;
            int x = s8 ^ (sr & 7);
            goffB[i] = (size_t)(bn + sr * 2 + (x >> 2)) * K + (x & 3) * 8;
            ldsoB[i] = (i * WAVES + w) * 512;
        }
    }
    int ra[M_REP], rb[4];
#pragma unroll
    for (int m = 0; m < M_REP; ++m) {
        int r = wr * Mw + m * 16 + l15;
        int s8 = (kgrp + 4 * (r & 1)) ^ ((r >> 1) & 7);
        ra[m] = (r >> 1) * 64 + s8 * 8;
    }
#pragma unroll
    for (int n = 0; n < 4; ++n) {
        int r = wc * 64 + n * 16 + l15;
        int s8 = (kgrp + 4 * (r & 1)) ^ ((r >> 1) & 7);
        rb[n] = (r >> 1) * 64 + s8 * 8;
    }

    f32x4 acc[M_REP][4] = {};

#define STG(t_, b_) do { size_t k0_ = (size_t)(t_) * 32;               \
    _Pragma("unroll")                                                  \
    for (int i_ = 0; i_ < NA; ++i_)                                    \
        gload_lds16(A + goffA[i_] + k0_, &Asm[b_][ldsoA[i_]]);         \
    _Pragma("unroll")                                                  \
    for (int i_ = 0; i_ < NB; ++i_)                                    \
        gload_lds16(Bt + goffB[i_] + k0_, &Bsm[b_][ldsoB[i_]]); } while (0)

    const int nT = K >> 5;
    STG(0, 0); STG(1, 1);
    WAITVM(NST);
    __builtin_amdgcn_s_barrier();

    int cur = 0;
    for (int tk = 0; tk < nT; ++tk) {
        s16x8 af[M_REP], bfr[4];
#pragma unroll
        for (int m = 0; m < M_REP; ++m)
            af[m] = *reinterpret_cast<const s16x8*>(&Asm[cur][ra[m]]);
#pragma unroll
        for (int n = 0; n < 4; ++n)
            bfr[n] = *reinterpret_cast<const s16x8*>(&Bsm[cur][rb[n]]);
        if (tk + 2 < nT) STG(tk + 2, cur == 0 ? 2 : cur - 1);
        __builtin_amdgcn_s_setprio(1);
#pragma unroll
        for (int m = 0; m < M_REP; ++m)
#pragma unroll
            for (int n = 0; n < 4; ++n)
                acc[m][n] = __builtin_amdgcn_mfma_f32_16x16x32_bf16(af[m], bfr[n], acc[m][n], 0, 0, 0);
        __builtin_amdgcn_s_setprio(0);
        if (tk + 2 < nT)      WAITVM(NST);
        else if (tk + 1 < nT) WAITVM(0);
        if (tk + 1 < nT) __builtin_amdgcn_s_barrier();
        cur = (cur == 2) ? 0 : cur + 1;
    }
#undef STG

    // fused per-head softmax epilogue (wave spans one 64-col head)
    float bqv[4], ksv[4], vsv[4];
#pragma unroll
    for (int n = 0; n < 4; ++n) {
        int col = bn + wc * 64 + n * 16 + l15;
        bqv[n] = bias[col];
        ksv[n] = kvsum[col];
        vsv[n] = kvsum[HDK + col];
    }
#pragma unroll
    for (int m = 0; m < M_REP; ++m) {
        int grow = bm + wr * Mw + m * 16 + kgrp * 4;
#pragma unroll
        for (int j = 0; j < 4; ++j) {
            float x[4];
#pragma unroll
            for (int n = 0; n < 4; ++n)
                x[n] = 0.125f * (acc[m][n][j] + bqv[n]) * ksv[n];
            float mx = fmaxf(fmaxf(x[0], x[1]), fmaxf(x[2], x[3]));
#pragma unroll
            for (int off = 8; off; off >>= 1) mx = fmaxf(mx, __shfl_xor(mx, off));
            float e[4], s = 0.f;
#pragma unroll
            for (int n = 0; n < 4; ++n) { e[n] = __expf(x[n] - mx); s += e[n]; }
#pragma unroll
            for (int off = 8; off; off >>= 1) s += __shfl_xor(s, off);
            float inv = 1.0f / s;
#pragma unroll
            for (int n = 0; n < 4; ++n) {
                int col = bn + wc * 64 + n * 16 + l15;
                R[(size_t)(grow + j) * N + col] = f2bf(e[n] * inv * vsv[n]);
            }
        }
    }
}

// ---------- GEMM2: B-direct (frags from global), A via LDS — LDS-pipe relief ----------
// Diagnosis (r5-r13): GEMM2 is LDS-throughput-bound — per CU-tile the LDS pipe
// serves ~144KB (96 b128 reads + staging writes) ≈ 1440cy vs MFMA 620cy; all
// schedule variants kept this traffic so all landed ~46us. Fix: B-fragments
// are 16B/lane k-contiguous in wo_t — load them DIRECTLY with one
// global_load_dwordx4 per frag (no LDS, no swizzle), register-double-buffered
// one tile ahead (bf0/bf1 named, rule #20; compiler auto-inserts vmcnt for
// reg consumers). A stays on the r10 gload_lds path (3-buf, involution
// swizzle). Manual counted vmcnt only guards the A path: steady-state 8
// younger vm-ops (4 B-frag + 4 A-stage per tile), 4 at drain edges.
// LDS ops/CU-tile: 144KB -> 96KB. B re-reads hit per-XCD L2 (rect swizzle).
template<int BMt, int BNt, int WM, int WN, int BMPX, int NXBN, int BNPX>
__global__ __launch_bounds__(WM * WN * 64, 2)
void gemm_bd(const unsigned short* __restrict__ A, const unsigned short* __restrict__ Bt,
             float* __restrict__ C, const float* __restrict__ bias, int N, int K) {
    constexpr int WAVES = WM * WN;
    constexpr int Mw = BMt / WM;
    constexpr int M_REP = Mw / 16;
    constexpr int NA = BMt * 32 / (WAVES * 512);   // A gloads per thread per stage (=4)
    static_assert(BNt / WN == 64, "wave col span must be 64");
    static_assert(NA == 4, "wait counts below assume NA == 4");

    __shared__ __align__(16) unsigned short Asm[3][BMt * 32];   // 3 x 16KB

    const int xcd = blockIdx.x & 7, l = blockIdx.x >> 3;
    const int bm = ((xcd / NXBN) * BMPX + (l % BMPX)) * BMt;
    const int bn = ((xcd % NXBN) * BNPX + (l / BMPX)) * BNt;

    const int t = threadIdx.x;
    const int w = t >> 6, lane = t & 63;
    const int wr = w / WN, wc = w % WN;
    const int l15 = lane & 15, kgrp = lane >> 4;

    // A staging map (r10 involution)
    size_t goffA[NA];
    int ldsoA[NA];
    {
        int s8 = lane & 7, jj = lane >> 3;
#pragma unroll
        for (int i = 0; i < NA; ++i) {
            int sr = (i * WAVES + w) * 8 + jj;
            int x = s8 ^ (sr & 7);
            goffA[i] = (size_t)(bm + sr * 2 + (x >> 2)) * K + (x & 3) * 8;
            ldsoA[i] = (i * WAVES + w) * 512;
        }
    }
    // A ds_read swizzled offsets
    int ra[M_REP];
#pragma unroll
    for (int m = 0; m < M_REP; ++m) {
        int r = wr * Mw + m * 16 + l15;
        int s8 = (kgrp + 4 * (r & 1)) ^ ((r >> 1) & 7);
        ra[m] = (r >> 1) * 64 + s8 * 8;
    }
    // B frag global offsets: frag n = 16B at row (bn + wc*64 + n*16 + l15), col kgrp*8
    size_t gBoff[4];
#pragma unroll
    for (int n = 0; n < 4; ++n)
        gBoff[n] = (size_t)(bn + wc * 64 + n * 16 + l15) * K + kgrp * 8;

    f32x4 acc[M_REP][4] = {};
    s16x8 bf0[4], bf1[4];

#define STAGE_A(t_, b_) do { size_t k0_ = (size_t)(t_) * 32;           \
    _Pragma("unroll")                                                  \
    for (int i_ = 0; i_ < NA; ++i_)                                    \
        gload_lds16(A + goffA[i_] + k0_, &Asm[b_][ldsoA[i_]]); } while (0)

#define LOADB(bf_, t_) do { _Pragma("unroll")                          \
    for (int n_ = 0; n_ < 4; ++n_)                                     \
        bf_[n_] = *reinterpret_cast<const s16x8*>(&Bt[gBoff[n_] + (size_t)(t_) * 32]); } while (0)

#define READA(b_) do { _Pragma("unroll")                               \
    for (int m_ = 0; m_ < M_REP; ++m_)                                 \
        af[m_] = *reinterpret_cast<const s16x8*>(&Asm[b_][ra[m_]]); } while (0)

#define MFMAS(bf_) do {                                                \
    __builtin_amdgcn_s_setprio(1);                                     \
    _Pragma("unroll")                                                  \
    for (int m_ = 0; m_ < M_REP; ++m_)                                 \
        _Pragma("unroll")                                              \
        for (int n_ = 0; n_ < 4; ++n_)                                 \
            acc[m_][n_] = __builtin_amdgcn_mfma_f32_16x16x32_bf16(     \
                af[m_], bf_[n_], acc[m_][n_], 0, 0, 0);                \
    __builtin_amdgcn_s_setprio(0); } while (0)

    const int nT = K >> 5;   // 32, even
    s16x8 af[M_REP];

    // prologue: B(0) frags, A tiles 0,1. Younger-than-Astage(0) = Astage(1) -> vmcnt(4)
    LOADB(bf0, 0);
    STAGE_A(0, 0); STAGE_A(1, 1);
    WAITVM(4);
    __builtin_amdgcn_s_barrier();

    int cur = 0;
    for (int tk = 0; tk < nT; tk += 2) {
        // even sub-iter: MFMA tile tk with bf0; prefetch B(tk+1), A(tk+2)
        READA(cur);
        if (tk + 1 < nT) LOADB(bf1, tk + 1);
        if (tk + 2 < nT) STAGE_A(tk + 2, cur == 0 ? 2 : cur - 1);
        MFMAS(bf0);
        if (tk + 1 < nT) {
            if (tk + 2 < nT) WAITVM(8); else WAITVM(4);   // Astage(tk+1) done
            __builtin_amdgcn_s_barrier();
        }
        cur = (cur == 2) ? 0 : cur + 1;
        // odd sub-iter (tk+1 < nT since nT even): MFMA with bf1
        READA(cur);
        if (tk + 2 < nT) LOADB(bf0, tk + 2);
        if (tk + 3 < nT) STAGE_A(tk + 3, cur == 0 ? 2 : cur - 1);
        MFMAS(bf1);
        if (tk + 2 < nT) {
            if (tk + 3 < nT) WAITVM(8); else WAITVM(4);   // Astage(tk+2) done
            __builtin_amdgcn_s_barrier();
        }
        cur = (cur == 2) ? 0 : cur + 1;
    }
#undef STAGE_A
#undef LOADB
#undef READA
#undef MFMAS

    // epilogue: C/D layout col = lane&15, row = (lane>>4)*4 + j
#pragma unroll
    for (int m = 0; m < M_REP; ++m) {
        int grow = bm + wr * Mw + m * 16 + kgrp * 4;
#pragma unroll
        for (int n = 0; n < 4; ++n) {
            int gcol = bn + wc * 64 + n * 16 + l15;
            float bb = bias[gcol];
#pragma unroll
            for (int j = 0; j < 4; ++j)
                C[(size_t)(grow + j) * N + gcol] = acc[m][n][j] + bb;
        }
    }
}

// ---------- host launch ----------
extern "C" void kernel_launch(void* const* d_in, const int* in_sizes, int n_in,
                              void* d_out, int out_size, void* d_ws, size_t ws_size,
                              hipStream_t stream) {
    const float* target = (const float*)d_in[0];
    const float* source = (const float*)d_in[1];
    const float* value  = (const float*)d_in[2];
    const float* Wq = (const float*)d_in[3];
    const float* bq = (const float*)d_in[4];
    const float* Wk = (const float*)d_in[5];
    const float* bk = (const float*)d_in[6];
    const float* Wv = (const float*)d_in[7];
    const float* bv = (const float*)d_in[8];
    const float* Wo = (const float*)d_in[9];
    const float* bo = (const float*)d_in[10];
    float* out = (float*)d_out;

    char* ws = (char*)d_ws;
    float*          part1  = (float*)(ws);                      // 1.25MB
    float*          part2  = (float*)(ws + 0x180000);           // 512KB
    float*          kvsum  = (float*)(ws + 0x210000);           // 8KB
    unsigned short* tgt_bf = (unsigned short*)(ws + 0x400000);  // 8MB
    unsigned short* wq_t   = (unsigned short*)(ws + 0xC00000);  // 2MB
    unsigned short* wo_t   = (unsigned short*)(ws + 0xE00000);  // 8MB
    unsigned short* Rb     = (unsigned short*)(ws + 0x1600000); // 8MB

    // 1) fused prep: colsum partials + cast(target) + transpose(Wq) + transpose(Wo)
    mega1<<<7488, 256, 0, stream>>>(source, value, part1, target, tgt_bf, Wq, wq_t, Wo, wo_t);

    // 2) Ksum/Vsum GEMV + bias fold
    gemv_partial2<<<dim3(4, 64, 2), 256, 0, stream>>>(Wk, Wv, part1, part2);
    gemv_reduce<<<8, 256, 0, stream>>>(part2, bk, bv, kvsum);

    // 3) fused: S = target @ Wq; R = softmax_head(0.125*(S+bq)*Ksum) * Vsum (bf16)
    //    r10's proven config: 64x128, grid 512, 2 blocks/CU.
    gemm_ctd3<1, 64, 128, 2, 2, 16, 2, 4><<<512, 256, 0, stream>>>(
        tgt_bf, wq_t, nullptr, bq, kvsum, Rb, HDK, DMODEL);

    // 4) out = R @ Wo + bo — B-direct: 256x128 blocks, 4 waves, grid 512,
    //    2 blocks/CU (48KB LDS each), rect 8bm x 8bn per XCD.
    gemm_bd<256, 128, 2, 2, 8, 4, 8><<<512, 256, 0, stream>>>(
        Rb, wo_t, out, bo, DLLM, HDK);
}

// Round 15
// 93.409 us; speedup vs baseline: 1.4643x; 1.1293x over previous
//
#include <hip/hip_runtime.h>

// ---------- constants (problem is fixed-shape) ----------
#define BB   16
#define PP   256
#define BP   4096        // B*P
#define DMODEL 1024
#define VV   1000
#define DLLM 4096
#define HH   16
#define DK   64
#define HDK  1024        // H*DK

using f32x4 = __attribute__((ext_vector_type(4))) float;
using s16x8 = __attribute__((ext_vector_type(8))) short;
using us8   = __attribute__((ext_vector_type(8))) unsigned short;

__device__ __forceinline__ unsigned short f2bf(float f) {
    unsigned int u = __builtin_bit_cast(unsigned int, f);
    u = (u + 0x7FFFu + ((u >> 16) & 1u)) >> 16;   // RNE
    return (unsigned short)u;
}

__device__ __forceinline__ void gload_lds16(const unsigned short* g, unsigned short* lds) {
    __builtin_amdgcn_global_load_lds(
        (const __attribute__((address_space(1))) void*)g,
        (__attribute__((address_space(3))) void*)lds,
        16, 0, 0);
}

#define WAITVM(n_) asm volatile("s_waitcnt vmcnt(%0)" :: "n"(n_) : "memory")

// ---------- MEGA1: colsum_partial ∪ cast_bf16 ∪ transpose(Wq) ∪ transpose(Wo) ----------
__device__ __forceinline__ void transpose_body(const float* __restrict__ src,
                                               unsigned short* __restrict__ dst,
                                               int R, int C, int bx, int by, int t,
                                               float (*tile)[33]) {
    int x = t & 7, y = t >> 3;                      // 8 x 32
    int c0 = bx * 32, r0 = by * 32;
    float4 v = *reinterpret_cast<const float4*>(&src[(size_t)(r0 + y) * C + c0 + x * 4]);
    tile[y][x * 4 + 0] = v.x; tile[y][x * 4 + 1] = v.y;
    tile[y][x * 4 + 2] = v.z; tile[y][x * 4 + 3] = v.w;
    __syncthreads();
    ushort4 o = make_ushort4(f2bf(tile[x * 4 + 0][y]), f2bf(tile[x * 4 + 1][y]),
                             f2bf(tile[x * 4 + 2][y]), f2bf(tile[x * 4 + 3][y]));
    *reinterpret_cast<ushort4*>(&dst[(size_t)(c0 + y) * R + r0 + x * 4]) = o;
}

__global__ void mega1(const float* __restrict__ src0, const float* __restrict__ src1,
                      float* __restrict__ part1,
                      const float* __restrict__ target, unsigned short* __restrict__ tgt_bf,
                      const float* __restrict__ Wq, unsigned short* __restrict__ wq_t,
                      const float* __restrict__ Wo, unsigned short* __restrict__ wo_t) {
    __shared__ float tile[32][33];
    int b = blockIdx.x, t = threadIdx.x;
    if (b < 320) {
        int z = b / 160, rem = b % 160, y = rem >> 2, x = rem & 3;
        int col4 = x * 256 + t;
        const float4* src = reinterpret_cast<const float4*>(z ? src1 : src0);
        int r0 = y * 25;
        float4 acc = make_float4(0.f, 0.f, 0.f, 0.f);
        for (int r = 0; r < 25; ++r) {
            float4 v = src[(size_t)(r0 + r) * (DLLM / 4) + col4];
            acc.x += v.x; acc.y += v.y; acc.z += v.z; acc.w += v.w;
        }
        reinterpret_cast<float4*>(part1)[(size_t)(z * 40 + y) * (DLLM / 4) + col4] = acc;
    } else if (b < 320 + 2048) {
        int idx = (b - 320) * 256 + t;
        float4 v0 = reinterpret_cast<const float4*>(target)[idx * 2];
        float4 v1 = reinterpret_cast<const float4*>(target)[idx * 2 + 1];
        us8 o = { f2bf(v0.x), f2bf(v0.y), f2bf(v0.z), f2bf(v0.w),
                  f2bf(v1.x), f2bf(v1.y), f2bf(v1.z), f2bf(v1.w) };
        *reinterpret_cast<us8*>(&tgt_bf[(size_t)idx * 8]) = o;
    } else if (b < 320 + 2048 + 1024) {
        int b2 = b - 2368;
        transpose_body(Wq, wq_t, DMODEL, HDK, b2 & 31, b2 >> 5, t, tile);
    } else {
        int b2 = b - 3392;
        transpose_body(Wo, wo_t, HDK, DLLM, b2 & 127, b2 >> 7, t, tile);
    }
}

// ---------- gemv_partial2 (inlines colsum_reduce) ----------
__global__ void gemv_partial2(const float* __restrict__ Wk, const float* __restrict__ Wv,
                              const float* __restrict__ part1, float* __restrict__ part2) {
    __shared__ float vec[64];
    int c     = blockIdx.x * 256 + threadIdx.x;
    int chunk = blockIdx.y;
    int z     = blockIdx.z;
    const float* W = z ? Wv : Wk;
    if (threadIdx.x < 64) {
        int r = chunk * 64 + threadIdx.x;
        float a = 0.f;
        for (int p = 0; p < 40; ++p)
            a += part1[(size_t)(z * 40 + p) * DLLM + r];
        vec[threadIdx.x] = a;
    }
    __syncthreads();
    float acc = 0.f;
    int r0 = chunk * 64;
    for (int r = 0; r < 64; ++r)
        acc += vec[r] * W[(size_t)(r0 + r) * HDK + c];
    part2[((z * 64 + chunk) * HDK) + c] = acc;
}

__global__ void gemv_reduce(const float* __restrict__ part,
                            const float* __restrict__ bk, const float* __restrict__ bv,
                            float* __restrict__ kvsum) {
    int idx = blockIdx.x * 256 + threadIdx.x;
    int z = idx >> 10, c = idx & 1023;
    float acc = 0.f;
    for (int ch = 0; ch < 64; ++ch) acc += part[(size_t)(z * 64 + ch) * HDK + c];
    acc += (float)VV * (z ? bv[c] : bk[c]);
    kvsum[idx] = acc;
}

// ---------- counted-vmcnt GEMM, 3-buffer BK=32, distance-2 prefetch ----------
// Best-of-14-rounds configuration, frozen:
//   GEMM2 = r7's exact kernel (44.64us measured): 256x128, 4 waves, grid 512,
//           2 blocks/CU, BIJECTIVE XCD swizzle (beats rect by 1.4us).
//   GEMM1 = r10's config (best measured): 64x128, 4 waves, grid 512, RECT swizzle.
// SWZ=0: bijective (gx = N-tiles); SWZ=1: rect BMPX x BNPX per XCD.
// LDS involution swizzle both sides (0 bank conflicts measured r4-r14).
// EPI=0: C(f32)=A*B^T+bias. EPI=1: fused per-head softmax -> bf16 R.
template<int EPI, int SWZ, int BMt, int BNt, int WM, int WN, int BMPX, int NXBN, int BNPX>
__global__ __launch_bounds__(WM * WN * 64, 2)
void gemm_ctd3(const unsigned short* __restrict__ A, const unsigned short* __restrict__ Bt,
               float* __restrict__ C, const float* __restrict__ bias,
               const float* __restrict__ kvsum, unsigned short* __restrict__ R,
               int N, int K, int gx) {
    constexpr int WAVES = WM * WN;
    constexpr int Mw = BMt / WM;
    constexpr int M_REP = Mw / 16;
    constexpr int NA = BMt * 32 / (WAVES * 512);
    constexpr int NB = BNt * 32 / (WAVES * 512);
    constexpr int NST = NA + NB;
    static_assert(BNt / WN == 64, "wave col span must be 64");
    static_assert(NA >= 1 && NB >= 1, "staging geometry");

    __shared__ __align__(16) unsigned short Asm[3][BMt * 32];
    __shared__ __align__(16) unsigned short Bsm[3][BNt * 32];

    int bm, bn;
    if (SWZ == 0) {
        // bijective XCD swizzle (grid % 8 == 0)
        const int q8 = gridDim.x >> 3;
        const int nb = (blockIdx.x & 7) * q8 + (blockIdx.x >> 3);
        bm = (nb / gx) * BMt;
        bn = (nb % gx) * BNt;
    } else {
        // rect-per-XCD swizzle
        const int xcd = blockIdx.x & 7, l = blockIdx.x >> 3;
        bm = ((xcd / NXBN) * BMPX + (l % BMPX)) * BMt;
        bn = ((xcd % NXBN) * BNPX + (l / BMPX)) * BNt;
    }

    const int t = threadIdx.x;
    const int w = t >> 6, lane = t & 63;
    const int wr = w / WN, wc = w % WN;
    const int l15 = lane & 15, kgrp = lane >> 4;

    // staging map: lane covers super-row +(lane>>3), phys slot lane&7;
    // global content for phys slot s at sr = (s ^ (sr&7)).
    size_t goffA[NA], goffB[NB];
    int ldsoA[NA], ldsoB[NB];
    {
        int s8 = lane & 7, jj = lane >> 3;
#pragma unroll
        for (int i = 0; i < NA; ++i) {
            int sr = (i * WAVES + w) * 8 + jj;
            int x = s8 ^ (sr & 7);
            goffA[i] = (size_t)(bm + sr * 2 + (x >> 2)) * K + (x & 3) * 8;
            ldsoA[i] = (i * WAVES + w) * 512;
        }
#pragma unroll
        for (int i = 0; i < NB; ++i) {
            int sr = (i * WAVES + w) * 8 + jj;
            int x = s8 ^ (sr & 7);
            goffB[i] = (size_t)(bn + sr * 2 + (x >> 2)) * K + (x & 3) * 8;
            ldsoB[i] = (i * WAVES + w) * 512;
        }
    }
    // swizzled ds_read offsets (ushort units)
    int ra[M_REP], rb[4];
#pragma unroll
    for (int m = 0; m < M_REP; ++m) {
        int r = wr * Mw + m * 16 + l15;
        int s8 = (kgrp + 4 * (r & 1)) ^ ((r >> 1) & 7);
        ra[m] = (r >> 1) * 64 + s8 * 8;
    }
#pragma unroll
    for (int n = 0; n < 4; ++n) {
        int r = wc * 64 + n * 16 + l15;
        int s8 = (kgrp + 4 * (r & 1)) ^ ((r >> 1) & 7);
        rb[n] = (r >> 1) * 64 + s8 * 8;
    }

    f32x4 acc[M_REP][4] = {};

#define STG(t_, b_) do { size_t k0_ = (size_t)(t_) * 32;               \
    _Pragma("unroll")                                                  \
    for (int i_ = 0; i_ < NA; ++i_)                                    \
        gload_lds16(A + goffA[i_] + k0_, &Asm[b_][ldsoA[i_]]);         \
    _Pragma("unroll")                                                  \
    for (int i_ = 0; i_ < NB; ++i_)                                    \
        gload_lds16(Bt + goffB[i_] + k0_, &Bsm[b_][ldsoB[i_]]); } while (0)

    const int nT = K >> 5;
    STG(0, 0); STG(1, 1);
    WAITVM(NST);
    __builtin_amdgcn_s_barrier();

    int cur = 0;
    for (int tk = 0; tk < nT; ++tk) {
        s16x8 af[M_REP], bfr[4];
#pragma unroll
        for (int m = 0; m < M_REP; ++m)
            af[m] = *reinterpret_cast<const s16x8*>(&Asm[cur][ra[m]]);
#pragma unroll
        for (int n = 0; n < 4; ++n)
            bfr[n] = *reinterpret_cast<const s16x8*>(&Bsm[cur][rb[n]]);
        if (tk + 2 < nT) STG(tk + 2, cur == 0 ? 2 : cur - 1);   // (cur+2)%3
        __builtin_amdgcn_s_setprio(1);
#pragma unroll
        for (int m = 0; m < M_REP; ++m)
#pragma unroll
            for (int n = 0; n < 4; ++n)
                acc[m][n] = __builtin_amdgcn_mfma_f32_16x16x32_bf16(af[m], bfr[n], acc[m][n], 0, 0, 0);
        __builtin_amdgcn_s_setprio(0);
        if (tk + 2 < nT)      WAITVM(NST);
        else if (tk + 1 < nT) WAITVM(0);
        if (tk + 1 < nT) __builtin_amdgcn_s_barrier();
        cur = (cur == 2) ? 0 : cur + 1;
    }
#undef STG

    // epilogue: C/D layout col = lane&15, row = (lane>>4)*4 + j
    if (EPI == 0) {
#pragma unroll
        for (int m = 0; m < M_REP; ++m) {
            int grow = bm + wr * Mw + m * 16 + kgrp * 4;
#pragma unroll
            for (int n = 0; n < 4; ++n) {
                int gcol = bn + wc * 64 + n * 16 + l15;
                float bb = bias[gcol];
#pragma unroll
                for (int j = 0; j < 4; ++j)
                    C[(size_t)(grow + j) * N + gcol] = acc[m][n][j] + bb;
            }
        }
    } else {
        // wave's 64-col span = one head: softmax over head dim, scale by Vsum
        float bqv[4], ksv[4], vsv[4];
#pragma unroll
        for (int n = 0; n < 4; ++n) {
            int col = bn + wc * 64 + n * 16 + l15;
            bqv[n] = bias[col];
            ksv[n] = kvsum[col];
            vsv[n] = kvsum[HDK + col];
        }
#pragma unroll
        for (int m = 0; m < M_REP; ++m) {
            int grow = bm + wr * Mw + m * 16 + kgrp * 4;
#pragma unroll
            for (int j = 0; j < 4; ++j) {
                float x[4];
#pragma unroll
                for (int n = 0; n < 4; ++n)
                    x[n] = 0.125f * (acc[m][n][j] + bqv[n]) * ksv[n];
                float mx = fmaxf(fmaxf(x[0], x[1]), fmaxf(x[2], x[3]));
#pragma unroll
                for (int off = 8; off; off >>= 1) mx = fmaxf(mx, __shfl_xor(mx, off));
                float e[4], s = 0.f;
#pragma unroll
                for (int n = 0; n < 4; ++n) { e[n] = __expf(x[n] - mx); s += e[n]; }
#pragma unroll
                for (int off = 8; off; off >>= 1) s += __shfl_xor(s, off);
                float inv = 1.0f / s;
#pragma unroll
                for (int n = 0; n < 4; ++n) {
                    int col = bn + wc * 64 + n * 16 + l15;
                    R[(size_t)(grow + j) * N + col] = f2bf(e[n] * inv * vsv[n]);
                }
            }
        }
    }
}

// ---------- host launch ----------
extern "C" void kernel_launch(void* const* d_in, const int* in_sizes, int n_in,
                              void* d_out, int out_size, void* d_ws, size_t ws_size,
                              hipStream_t stream) {
    const float* target = (const float*)d_in[0];
    const float* source = (const float*)d_in[1];
    const float* value  = (const float*)d_in[2];
    const float* Wq = (const float*)d_in[3];
    const float* bq = (const float*)d_in[4];
    const float* Wk = (const float*)d_in[5];
    const float* bk = (const float*)d_in[6];
    const float* Wv = (const float*)d_in[7];
    const float* bv = (const float*)d_in[8];
    const float* Wo = (const float*)d_in[9];
    const float* bo = (const float*)d_in[10];
    float* out = (float*)d_out;

    char* ws = (char*)d_ws;
    float*          part1  = (float*)(ws);                      // 1.25MB
    float*          part2  = (float*)(ws + 0x180000);           // 512KB
    float*          kvsum  = (float*)(ws + 0x210000);           // 8KB
    unsigned short* tgt_bf = (unsigned short*)(ws + 0x400000);  // 8MB
    unsigned short* wq_t   = (unsigned short*)(ws + 0xC00000);  // 2MB
    unsigned short* wo_t   = (unsigned short*)(ws + 0xE00000);  // 8MB
    unsigned short* Rb     = (unsigned short*)(ws + 0x1600000); // 8MB

    // 1) fused prep: colsum partials + cast(target) + transpose(Wq) + transpose(Wo)
    mega1<<<7488, 256, 0, stream>>>(source, value, part1, target, tgt_bf, Wq, wq_t, Wo, wo_t);

    // 2) Ksum/Vsum GEMV + bias fold
    gemv_partial2<<<dim3(4, 64, 2), 256, 0, stream>>>(Wk, Wv, part1, part2);
    gemv_reduce<<<8, 256, 0, stream>>>(part2, bk, bv, kvsum);

    // 3) fused: S = target @ Wq; R = softmax_head(0.125*(S+bq)*Ksum) * Vsum (bf16)
    //    r10's best-measured GEMM1: 64x128, 4 waves, grid 512, rect swizzle.
    gemm_ctd3<1, 1, 64, 128, 2, 2, 16, 2, 4><<<512, 256, 0, stream>>>(
        tgt_bf, wq_t, nullptr, bq, kvsum, Rb, HDK, DMODEL, 0);

    // 4) out = R @ Wo + bo
    //    r7's best-measured GEMM2 (44.64us): 256x128, 4 waves, grid 512,
    //    bijective XCD swizzle (gx = 4096/128 = 32), cached stores.
    gemm_ctd3<0, 0, 256, 128, 2, 2, 0, 0, 0><<<512, 256, 0, stream>>>(
        Rb, wo_t, out, bo, nullptr, nullptr, DLLM, HDK, DLLM / 128);
}